// Round 4
// baseline (60.772 us; speedup 1.0000x reference)
//
#include <hip/hip_runtime.h>
#include <hip/hip_bf16.h>
#include <stdint.h>

// Problem constants
#define BATCH 32
#define CIN   64
#define COUT  64
#define HIN   58
#define WIN   58
#define HOUT  56
#define WOUT  56
#define RSIZE 512
#define NB    10
#define EDIM  64
#define HID   128
#define CHW   (HIN*WIN)     // 3364
#define OHW   (HOUT*WOUT)   // 3136

typedef __attribute__((ext_vector_type(8)))  short short8;
typedef __attribute__((ext_vector_type(16))) float f32x16;

__device__ __forceinline__ unsigned short f2bf(float f) {
    unsigned int u = __builtin_bit_cast(unsigned int, f);
    u += 0x7fffu + ((u >> 16) & 1u);          // RNE
    return (unsigned short)(u >> 16);
}

// ---------------- Kernel A: routing -> softmax weights ----------------
__global__ __launch_bounds__(128) void routing_kernel(
    const float* __restrict__ rv, const float* __restrict__ W1,
    const float* __restrict__ b1, const float* __restrict__ W2,
    const float* __restrict__ b2, const float* __restrict__ emb,
    float* __restrict__ weights_out)
{
    const int b = blockIdx.x;
    const int t = threadIdx.x;
    __shared__ float s_rv[RSIZE];
    __shared__ float s_h[HID];
    __shared__ float s_r[EDIM];
    __shared__ float s_rnorm;
    __shared__ float s_sim[16];

    for (int i = t; i < RSIZE; i += 128) s_rv[i] = rv[b * RSIZE + i];
    __syncthreads();

    {
        float acc = b1[t];
        for (int k = 0; k < RSIZE; ++k) acc = fmaf(s_rv[k], W1[k * HID + t], acc);
        s_h[t] = fmaxf(acc, 0.0f);
    }
    __syncthreads();

    if (t < EDIM) {
        float acc = b2[t];
        for (int j = 0; j < HID; ++j) acc = fmaf(s_h[j], W2[j * EDIM + t], acc);
        s_r[t] = acc;
        float sq = acc * acc;
        #pragma unroll
        for (int off = 32; off > 0; off >>= 1) sq += __shfl_xor(sq, off);
        if (t == 0) s_rnorm = sqrtf(sq);
    }
    __syncthreads();

    if (t < NB) {
        float dot = 0.0f, nb2 = 0.0f;
        for (int e = 0; e < EDIM; ++e) {
            float ev = emb[t * EDIM + e];
            dot = fmaf(ev, s_r[e], dot);
            nb2 = fmaf(ev, ev, nb2);
        }
        s_sim[t] = dot / ((s_rnorm + 1e-8f) * (sqrtf(nb2) + 1e-8f));
    }
    __syncthreads();

    if (t == 0) {
        float m = -1e30f;
        #pragma unroll
        for (int n = 0; n < NB; ++n) m = fmaxf(m, s_sim[n]);
        float w[NB];
        float sum = 0.0f;
        #pragma unroll
        for (int n = 0; n < NB; ++n) { w[n] = __expf(s_sim[n] - m); sum += w[n]; }
        float inv = 1.0f / sum;
        float d = 0.0f;
        #pragma unroll
        for (int n = 0; n < NB; ++n) { w[n] *= inv; d += w[n]; }
        float invd = 1.0f / d;
        #pragma unroll
        for (int n = 0; n < NB; ++n) weights_out[b * NB + n] = w[n] * invd;
    }
}

// ---------------- Kernel X: x fp32 [b][cin][sp] -> xb bf16 [b][sp][cin] ----------------
// grid = 32 * 53 blocks; block = (b, 64-sp chunk). LDS transpose tile.
__global__ __launch_bounds__(256, 2) void xcast_kernel(
    const float* __restrict__ x, unsigned short* __restrict__ xb)
{
    const int blk = blockIdx.x;
    const int b   = blk / 53;
    const int ch  = blk - b * 53;
    const int sp0 = ch * 64;
    const int n   = (sp0 + 64 <= CHW) ? 64 : (CHW - sp0);   // 64 or 36
    const int t   = threadIdx.x;

    __shared__ float sf[64][65];

    const float* xg = x + (size_t)b * CIN * CHW + sp0;
    const int nf4 = n >> 2;                                  // 16 or 9
    for (int i = t; i < 64 * nf4; i += 256) {
        const int c = i / nf4, f4 = i - c * nf4;
        const float4 v = *(const float4*)(xg + (size_t)c * CHW + f4 * 4);
        sf[c][f4 * 4 + 0] = v.x; sf[c][f4 * 4 + 1] = v.y;
        sf[c][f4 * 4 + 2] = v.z; sf[c][f4 * 4 + 3] = v.w;
    }
    __syncthreads();

    unsigned short* ob = xb + ((size_t)b * CHW + sp0) * 64;
    for (int j = t; j < n * 8; j += 256) {
        const int sp_l = j >> 3, cb = j & 7;
        short8 v;
        #pragma unroll
        for (int q = 0; q < 8; ++q) v[q] = (short)f2bf(sf[cb * 8 + q][sp_l]);
        *(short8*)(ob + sp_l * 64 + cb * 8) = v;
    }
}

// ---------------- Kernel B: mix weights -> bf16 [b][co][shift][cin] ----------------
__global__ __launch_bounds__(256) void wmixb_kernel(
    const float* __restrict__ cw, const float* __restrict__ cbias,
    const float* __restrict__ wts,
    unsigned short* __restrict__ weffb, float* __restrict__ sbias_g)
{
    const int co = blockIdx.x & 63;
    const int bq = blockIdx.x >> 6;
    const int t  = threadIdx.x;
    __shared__ float scw[NB * 576];
    __shared__ float sw[8 * NB];

    if (t < 8 * NB) sw[t] = wts[(bq * 8) * NB + t];
    for (int i = t; i < NB * 576; i += 256) {
        const int n = i / 576, rem = i - n * 576;
        scw[i] = cw[(size_t)(n * COUT + co) * 576 + rem];
    }
    __syncthreads();

    for (int i = t; i < 8 * 576; i += 256) {
        const int bl = i / 576, rem = i - bl * 576;
        const int s = rem >> 6, cin = rem & 63;
        float v = 0.0f;
        #pragma unroll
        for (int n = 0; n < NB; ++n)
            v = fmaf(sw[bl * NB + n], scw[n * 576 + cin * 9 + s], v);
        const int b = bq * 8 + bl;
        weffb[(((size_t)b * COUT + co) * 9 + s) * 64 + cin] = f2bf(v);
    }
    if (t < 8) {
        const int b = bq * 8 + t;
        float v = 0.0f;
        #pragma unroll
        for (int n = 0; n < NB; ++n) v = fmaf(sw[t * NB + n], cbias[n * COUT + co], v);
        sbias_g[b * COUT + co] = v;
    }
}

// ---------------- Kernel C: MFMA conv from pre-cast xb ----------------
// 896 blocks (b, 2-row tile), XCD-swizzled. 256 thr = 4 waves (mt, nh).
// LDS xs: [232 sp][8 slots of 8cin] bf16, slot = cb ^ (sp&7)  (XOR swizzle,
// both-sides: pre-swizzled global_load_lds source + swizzled ds_read).
__global__ __launch_bounds__(256, 3) void conv_mfma2_kernel(
    const unsigned short* __restrict__ xb, const unsigned short* __restrict__ weffb,
    const float* __restrict__ sbias_g, float* __restrict__ out)
{
    const int bid  = blockIdx.x;
    const int xcd  = bid & 7;
    const int slot = bid >> 3;
    const int b    = xcd + 8 * (slot / 28);
    const int tile = slot - (slot / 28) * 28;
    const int oh0  = tile * 2;

    const int t    = threadIdx.x;
    const int wid  = t >> 6;
    const int lane = t & 63;
    const int ln   = lane & 31;
    const int kg   = lane >> 5;
    const int mt   = wid & 1;
    const int nh   = wid >> 1;

    __shared__ unsigned short xs[232 * 64];   // 29696 B
    __shared__ float sbias[COUT];

    if (t < COUT) sbias[t] = sbias_g[b * COUT + t];

    // ---- stage whole 232sp x 64cin tile via global_load_lds, swizzled src ----
    const unsigned short* xgb = xb + ((size_t)b * CHW + oh0 * WIN) * 64;
    #pragma unroll
    for (int k = 0; k < 8; ++k) {
        if (k < 7 || t < 64) {                    // 1856 units total, wave-uniform tail
            const int u  = t + 256 * k;
            const int sp = u >> 3, jj = u & 7;
            const int cb = jj ^ (sp & 7);
            const int ubase = (t & ~63) + 256 * k;    // wave-uniform LDS base
            __builtin_amdgcn_global_load_lds(
                (const __attribute__((address_space(1))) void*)(xgb + sp * 64 + cb * 8),
                (__attribute__((address_space(3))) void*)(xs + ubase * 8),
                16, 0, 0);
        }
    }
    __syncthreads();

    // ---- per-lane B spatial bases ----
    int sbase[2]; int pq[2]; bool val[2];
    #pragma unroll
    for (int nt = 0; nt < 2; ++nt) {
        const int p = (nh * 2 + nt) * 32 + ln;
        val[nt] = (p < 112);
        const int pc = val[nt] ? p : 111;
        pq[nt] = pc;
        const int r = pc / 56, ow = pc - r * 56;
        sbase[nt] = r * WIN + ow;
    }

    f32x16 acc[2];
    #pragma unroll
    for (int nt = 0; nt < 2; ++nt)
        #pragma unroll
        for (int j = 0; j < 16; ++j) acc[nt][j] = 0.0f;

    const unsigned short* wbase =
        weffb + ((size_t)(b * COUT + mt * 32 + ln) * 9) * 64 + kg * 8;

    #pragma unroll
    for (int ks = 0; ks < 4; ++ks) {
        short8 af[9];
        #pragma unroll
        for (int s = 0; s < 9; ++s)
            af[s] = *(const short8*)(wbase + s * 64 + ks * 16);

        #pragma unroll
        for (int s = 0; s < 9; ++s) {
            const int kh = s / 3, kw = s - kh * 3;
            const int off = kh * WIN + kw;
            #pragma unroll
            for (int nt = 0; nt < 2; ++nt) {
                const int sp   = sbase[nt] + off;
                const int addr = (sp << 7) + ((ks * 32 + kg * 16) ^ ((sp & 7) << 4));
                const short8 bf = *(const short8*)((const char*)xs + addr);
                acc[nt] = __builtin_amdgcn_mfma_f32_32x32x16_bf16(af[s], bf, acc[nt], 0, 0, 0);
            }
        }
    }

    // ---- epilogue: row = (reg&3)+8*(reg>>2)+4*kg, col = ln ----
    #pragma unroll
    for (int nt = 0; nt < 2; ++nt) {
        if (!val[nt]) continue;
        const int p = pq[nt];
        const int r = p / 56, ow = p - r * 56;
        float* op = out + ((size_t)(b * COUT + mt * 32) * HOUT + oh0 + r) * WOUT + ow;
        #pragma unroll
        for (int reg = 0; reg < 16; ++reg) {
            const int co_l = (reg & 3) + 8 * (reg >> 2) + 4 * kg;
            op[(size_t)co_l * OHW] = acc[nt][reg] + sbias[mt * 32 + co_l];
        }
    }
}

// ---------------- Fallback (R3): MFMA conv converting x on the fly ----------------
#define LDSP 40
__global__ __launch_bounds__(256, 2) void conv_mfma_kernel(
    const float* __restrict__ x, const unsigned short* __restrict__ weffb,
    const float* __restrict__ sbias_g, float* __restrict__ out)
{
    const int bid  = blockIdx.x;
    const int xcd  = bid & 7;
    const int slot = bid >> 3;
    const int b    = xcd + 8 * (slot / 28);
    const int tile = slot - (slot / 28) * 28;
    const int oh0  = tile * 2;

    const int t    = threadIdx.x;
    const int wid  = t >> 6;
    const int lane = t & 63;
    const int ln   = lane & 31;
    const int kg   = lane >> 5;
    const int mt   = wid & 1;
    const int nh   = wid >> 1;

    __shared__ unsigned short xs[232 * LDSP];
    __shared__ float sbias[COUT];

    if (t < COUT) sbias[t] = sbias_g[b * COUT + t];

    int boff[2]; int pq[2]; bool val[2];
    #pragma unroll
    for (int nt = 0; nt < 2; ++nt) {
        const int p = (nh * 2 + nt) * 32 + ln;
        val[nt] = (p < 112);
        const int pc = val[nt] ? p : 111;
        pq[nt] = pc;
        const int r = pc / 56, ow = pc - r * 56;
        boff[nt] = (r * WIN + ow) * LDSP + kg * 8;
    }

    f32x16 acc[2];
    #pragma unroll
    for (int nt = 0; nt < 2; ++nt)
        #pragma unroll
        for (int j = 0; j < 16; ++j) acc[nt][j] = 0.0f;

    const float* xg = x + (size_t)b * CIN * CHW + oh0 * WIN;
    const int wrow = (b * COUT + mt * 32 + ln) * 9;

    for (int cc = 0; cc < 2; ++cc) {
        __syncthreads();
        #pragma unroll
        for (int i = 0; i < 4; ++i) {
            const int e = t + 256 * i;
            if (e < 928) {
                const int cb = e / 232;
                const int sp = e - cb * 232;
                const float* gp = xg + (size_t)(cc * 32 + cb * 8) * CHW + sp;
                short8 v;
                #pragma unroll
                for (int j = 0; j < 8; ++j)
                    v[j] = (short)f2bf(gp[(size_t)j * CHW]);
                *(short8*)&xs[sp * LDSP + cb * 8] = v;
            }
        }
        __syncthreads();

        #pragma unroll
        for (int ks = 0; ks < 2; ++ks) {
            short8 af[9];
            const unsigned short* wb = weffb + (size_t)wrow * 64 + cc * 32 + ks * 16 + kg * 8;
            #pragma unroll
            for (int s = 0; s < 9; ++s)
                af[s] = *(const short8*)(wb + s * 64);

            #pragma unroll
            for (int s = 0; s < 9; ++s) {
                const int kh = s / 3, kw = s - kh * 3;
                const int soff = (kh * WIN + kw) * LDSP + ks * 16;
                #pragma unroll
                for (int nt = 0; nt < 2; ++nt) {
                    const short8 bf = *(const short8*)&xs[boff[nt] + soff];
                    acc[nt] = __builtin_amdgcn_mfma_f32_32x32x16_bf16(af[s], bf, acc[nt], 0, 0, 0);
                }
            }
        }
    }

    #pragma unroll
    for (int nt = 0; nt < 2; ++nt) {
        if (!val[nt]) continue;
        const int p = pq[nt];
        const int r = p / 56, ow = p - r * 56;
        float* op = out + ((size_t)(b * COUT + mt * 32) * HOUT + oh0 + r) * WOUT + ow;
        #pragma unroll
        for (int reg = 0; reg < 16; ++reg) {
            const int co_l = (reg & 3) + 8 * (reg >> 2) + 4 * kg;
            op[(size_t)co_l * OHW] = acc[nt][reg] + sbias[mt * 32 + co_l];
        }
    }
}

extern "C" void kernel_launch(void* const* d_in, const int* in_sizes, int n_in,
                              void* d_out, int out_size, void* d_ws, size_t ws_size,
                              hipStream_t stream) {
    const float* x    = (const float*)d_in[0];
    const float* rv   = (const float*)d_in[1];
    const float* W1   = (const float*)d_in[2];
    const float* b1   = (const float*)d_in[3];
    const float* W2   = (const float*)d_in[4];
    const float* b2   = (const float*)d_in[5];
    const float* emb  = (const float*)d_in[6];
    const float* cw   = (const float*)d_in[7];
    const float* cb   = (const float*)d_in[8];
    float* out = (float*)d_out;

    // ws layout (floats): wts@0 (320) | sbias@1024 (2048) | weffb@3072 (589824) | xb@592896 (3444736)
    float* wts            = (float*)d_ws;
    float* sbias_g        = (float*)d_ws + 1024;
    unsigned short* weffb = (unsigned short*)((float*)d_ws + 3072);
    unsigned short* xb    = (unsigned short*)((float*)d_ws + 592896);

    const size_t need1 = (size_t)(592896 + 3444736) * sizeof(float);   // ~16.2 MB
    const size_t need2 = (size_t)(3072 + 589824) * sizeof(float);      // ~2.4 MB

    routing_kernel<<<dim3(BATCH), dim3(128), 0, stream>>>(rv, W1, b1, W2, b2, emb, wts);

    if (ws_size >= need1) {
        xcast_kernel<<<dim3(BATCH * 53), dim3(256), 0, stream>>>(x, xb);
        wmixb_kernel<<<dim3(256), dim3(256), 0, stream>>>(cw, cb, wts, weffb, sbias_g);
        conv_mfma2_kernel<<<dim3(BATCH * 28), dim3(256), 0, stream>>>(xb, weffb, sbias_g, out);
    } else if (ws_size >= need2) {
        wmixb_kernel<<<dim3(256), dim3(256), 0, stream>>>(cw, cb, wts, weffb, sbias_g);
        conv_mfma_kernel<<<dim3(BATCH * 28), dim3(256), 0, stream>>>(x, weffb, sbias_g, out);
    }
}

// Round 5
// 49.590 us; speedup vs baseline: 1.2255x; 1.2255x over previous
//
#include <hip/hip_runtime.h>
#include <hip/hip_bf16.h>
#include <stdint.h>

// Problem constants
#define BATCH 32
#define CIN   64
#define COUT  64
#define HIN   58
#define WIN   58
#define HOUT  56
#define WOUT  56
#define RSIZE 512
#define NB    10
#define EDIM  64
#define HID   128
#define CHW   (HIN*WIN)     // 3364
#define OHW   (HOUT*WOUT)   // 3136

typedef __attribute__((ext_vector_type(8)))  short short8;
typedef __attribute__((ext_vector_type(16))) float f32x16;

__device__ __forceinline__ unsigned short f2bf(float f) {
    unsigned int u = __builtin_bit_cast(unsigned int, f);
    u += 0x7fffu + ((u >> 16) & 1u);          // RNE
    return (unsigned short)(u >> 16);
}

// ---------------- Kernel 1: fused routing + weight-mix ----------------
// grid = 256 blocks: co = blk & 63, bq = blk >> 6 (8 batches each).
// Each block recomputes routing for its 8 batches (bitwise-identical math
// across blocks), then mixes expert weights for its co into weffb with the
// conv-coalesced layout [b][s][ks][kg][co][8cin], plus sbias.
__global__ __launch_bounds__(256) void prep_kernel(
    const float* __restrict__ rv, const float* __restrict__ W1,
    const float* __restrict__ b1, const float* __restrict__ W2,
    const float* __restrict__ b2, const float* __restrict__ emb,
    const float* __restrict__ cw, const float* __restrict__ cbias,
    unsigned short* __restrict__ weffb, float* __restrict__ sbias_g)
{
    const int co = blockIdx.x & 63;
    const int bq = blockIdx.x >> 6;
    const int t  = threadIdx.x;

    __shared__ float s_rv[8][RSIZE];     // 16 KB
    __shared__ float scw[NB * 576];      // 23 KB  (cw[n][co] slice, [cin*9+s])
    __shared__ float s_h[8][HID];        // 4 KB
    __shared__ float s_r[8][EDIM];       // 2 KB
    __shared__ float s_sim[8][NB];
    __shared__ float s_rn[8];
    __shared__ float s_w[8][NB];

    // stage cw slice (coalesced float4): NB*576 floats = 1440 f4
    for (int i = t; i < 1440; i += 256) {
        const int n = i / 144, r4 = i - n * 144;
        ((float4*)scw)[(size_t)n * 144 + r4] =
            *(const float4*)(cw + (size_t)(n * COUT + co) * 576 + r4 * 4);
    }
    // stage rv for 8 batches: 1024 f4
    for (int i = t; i < 1024; i += 256)
        ((float4*)&s_rv[0][0])[i] = *(const float4*)(rv + (size_t)bq * 8 * RSIZE + i * 4);
    __syncthreads();

    // hidden = relu(rv @ W1 + b1): h = t&127, half = t>>7 -> bl = half*4 + j
    {
        const int h = t & 127, half = t >> 7;
        float a0 = b1[h], a1 = a0, a2 = a0, a3 = a0;
        const float4* rv4 = (const float4*)&s_rv[0][0];
        for (int k4 = 0; k4 < 128; ++k4) {
            const float w0 = W1[(k4 * 4 + 0) * HID + h];
            const float w1 = W1[(k4 * 4 + 1) * HID + h];
            const float w2 = W1[(k4 * 4 + 2) * HID + h];
            const float w3 = W1[(k4 * 4 + 3) * HID + h];
            const float4 r0 = rv4[(half * 4 + 0) * 128 + k4];
            const float4 r1 = rv4[(half * 4 + 1) * 128 + k4];
            const float4 r2 = rv4[(half * 4 + 2) * 128 + k4];
            const float4 r3 = rv4[(half * 4 + 3) * 128 + k4];
            a0 = fmaf(r0.w, w3, fmaf(r0.z, w2, fmaf(r0.y, w1, fmaf(r0.x, w0, a0))));
            a1 = fmaf(r1.w, w3, fmaf(r1.z, w2, fmaf(r1.y, w1, fmaf(r1.x, w0, a1))));
            a2 = fmaf(r2.w, w3, fmaf(r2.z, w2, fmaf(r2.y, w1, fmaf(r2.x, w0, a2))));
            a3 = fmaf(r3.w, w3, fmaf(r3.z, w2, fmaf(r3.y, w1, fmaf(r3.x, w0, a3))));
        }
        s_h[half * 4 + 0][h] = fmaxf(a0, 0.0f);
        s_h[half * 4 + 1][h] = fmaxf(a1, 0.0f);
        s_h[half * 4 + 2][h] = fmaxf(a2, 0.0f);
        s_h[half * 4 + 3][h] = fmaxf(a3, 0.0f);
    }
    __syncthreads();

    // r = h @ W2 + b2: e = t&63, g = t>>6 -> bl in {2g, 2g+1}
    {
        const int e = t & 63, g = t >> 6;
        float a0 = b2[e], a1 = b2[e];
        for (int k = 0; k < HID; ++k) {
            const float w = W2[k * EDIM + e];
            a0 = fmaf(s_h[2 * g + 0][k], w, a0);
            a1 = fmaf(s_h[2 * g + 1][k], w, a1);
        }
        s_r[2 * g + 0][e] = a0;
        s_r[2 * g + 1][e] = a1;
    }
    __syncthreads();

    if (t < 8) {
        float s = 0.0f;
        for (int e = 0; e < EDIM; ++e) s = fmaf(s_r[t][e], s_r[t][e], s);
        s_rn[t] = sqrtf(s);
    }
    __syncthreads();

    if (t < 8 * NB) {
        const int bl = t / NB, n = t - bl * NB;
        float dot = 0.0f, nb2 = 0.0f;
        for (int e = 0; e < EDIM; ++e) {
            const float ev = emb[n * EDIM + e];
            dot = fmaf(ev, s_r[bl][e], dot);
            nb2 = fmaf(ev, ev, nb2);
        }
        s_sim[bl][n] = dot / ((s_rn[bl] + 1e-8f) * (sqrtf(nb2) + 1e-8f));
    }
    __syncthreads();

    if (t < 8) {
        float m = -1e30f;
        #pragma unroll
        for (int n = 0; n < NB; ++n) m = fmaxf(m, s_sim[t][n]);
        float w[NB], sum = 0.0f;
        #pragma unroll
        for (int n = 0; n < NB; ++n) { w[n] = __expf(s_sim[t][n] - m); sum += w[n]; }
        const float inv = 1.0f / sum;
        float d = 0.0f;
        #pragma unroll
        for (int n = 0; n < NB; ++n) { w[n] *= inv; d += w[n]; }
        const float invd = 1.0f / d;
        #pragma unroll
        for (int n = 0; n < NB; ++n) s_w[t][n] = w[n] * invd;
    }
    __syncthreads();

    // mix -> weffb[b][s][ks][kg][co][8]
    for (int i = t; i < 8 * 576; i += 256) {
        const int bl  = i / 576, rem = i - bl * 576;
        const int s   = rem >> 6, cin = rem & 63;
        float v = 0.0f;
        #pragma unroll
        for (int n = 0; n < NB; ++n)
            v = fmaf(s_w[bl][n], scw[n * 576 + cin * 9 + s], v);
        const int b  = bq * 8 + bl;
        const int ks = cin >> 4, kg = (cin >> 3) & 1, c8 = cin & 7;
        weffb[((((size_t)(b * 9 + s) * 4 + ks) * 2 + kg) * 64 + co) * 8 + c8] = f2bf(v);
    }
    if (t < 8) {
        float v = 0.0f;
        #pragma unroll
        for (int n = 0; n < NB; ++n) v = fmaf(s_w[t][n], cbias[n * COUT + co], v);
        sbias_g[(bq * 8 + t) * COUT + co] = v;
    }
}

// ---------------- Kernel 2: MFMA implicit-GEMM conv ----------------
// 896 blocks = 32 batches x 28 two-row tiles, XCD-swizzled (batch -> XCD for
// halo L2 reuse). 256 thr = 4 waves; wave wid owns n-tile p = wid*32+ln and
// BOTH co-halves (B-frag feeds 2 MFMAs). Inline fp32->bf16 staging into
// XOR-swizzled LDS [232 sp][slot=cb^(sp&7)][8cin] (uniform over 8 slots:
// conflict-free b128 on both sides).
__global__ __launch_bounds__(256, 2) void conv3_kernel(
    const float* __restrict__ x, const unsigned short* __restrict__ weffb,
    const float* __restrict__ sbias_g, float* __restrict__ out)
{
    const int bid  = blockIdx.x;
    const int xcd  = bid & 7;
    const int slot = bid >> 3;
    const int b    = xcd + 8 * (slot / 28);
    const int tile = slot - (slot / 28) * 28;
    const int oh0  = tile * 2;

    const int t    = threadIdx.x;
    const int wid  = t >> 6;
    const int lane = t & 63;
    const int ln   = lane & 31;
    const int kg   = lane >> 5;

    __shared__ unsigned short xs[232 * 64];   // 29696 B
    __shared__ float sbias[COUT];

    if (t < COUT) sbias[t] = sbias_g[b * COUT + t];

    // ---- stage full 232sp x 64cin tile, converting fp32->bf16 inline ----
    const float* xg = x + (size_t)b * CIN * CHW + oh0 * WIN;
    #pragma unroll
    for (int k = 0; k < 8; ++k) {
        const int e = t + 256 * k;
        if (e < 1856) {                       // 8 cin-blocks * 232 sp
            const int cb = e / 232;
            const int sp = e - cb * 232;
            const float* gp = xg + (size_t)(cb * 8) * CHW + sp;
            short8 v;
            #pragma unroll
            for (int j = 0; j < 8; ++j)
                v[j] = (short)f2bf(gp[(size_t)j * CHW]);
            *(short8*)&xs[sp * 64 + (cb ^ (sp & 7)) * 8] = v;
        }
    }
    __syncthreads();

    // ---- per-lane B spatial base ----
    const int p   = wid * 32 + ln;            // 0..127, valid < 112
    const bool valid = (p < 112);
    const int pc  = valid ? p : 111;
    const int r   = pc / 56, ow = pc - r * 56;
    const int sbase = r * WIN + ow;

    f32x16 acc[2];
    #pragma unroll
    for (int mt = 0; mt < 2; ++mt)
        #pragma unroll
        for (int j = 0; j < 16; ++j) acc[mt][j] = 0.0f;

    #pragma unroll
    for (int ks = 0; ks < 4; ++ks) {
        #pragma unroll
        for (int s = 0; s < 9; ++s) {
            const int kh = s / 3, kw = s - kh * 3;
            // A-loads: [b][s][ks][kg][co][8] -> 2 contiguous 512B segs / wave
            const unsigned short* ap =
                weffb + (((size_t)(b * 9 + s) * 4 + ks) * 2 + kg) * 512;
            const short8 a0 = *(const short8*)(ap + ln * 8);
            const short8 a1 = *(const short8*)(ap + (32 + ln) * 8);
            // B-read: swizzled LDS
            const int sp   = sbase + kh * WIN + kw;
            const int addr = (sp << 7) + ((((ks << 1) + kg) ^ (sp & 7)) << 4);
            const short8 bf = *(const short8*)((const char*)xs + addr);
            acc[0] = __builtin_amdgcn_mfma_f32_32x32x16_bf16(a0, bf, acc[0], 0, 0, 0);
            acc[1] = __builtin_amdgcn_mfma_f32_32x32x16_bf16(a1, bf, acc[1], 0, 0, 0);
        }
    }

    // ---- epilogue: D col = ln (spatial), row = (reg&3)+8*(reg>>2)+4*kg (co) ----
    if (valid) {
        #pragma unroll
        for (int mt = 0; mt < 2; ++mt) {
            float* op = out + ((size_t)(b * COUT + mt * 32) * HOUT + oh0 + r) * WOUT + ow;
            #pragma unroll
            for (int reg = 0; reg < 16; ++reg) {
                const int co_l = (reg & 3) + 8 * (reg >> 2) + 4 * kg;
                op[(size_t)co_l * OHW] = acc[mt][reg] + sbias[mt * 32 + co_l];
            }
        }
    }
}

extern "C" void kernel_launch(void* const* d_in, const int* in_sizes, int n_in,
                              void* d_out, int out_size, void* d_ws, size_t ws_size,
                              hipStream_t stream) {
    const float* x    = (const float*)d_in[0];
    const float* rv   = (const float*)d_in[1];
    const float* W1   = (const float*)d_in[2];
    const float* b1   = (const float*)d_in[3];
    const float* W2   = (const float*)d_in[4];
    const float* b2   = (const float*)d_in[5];
    const float* emb  = (const float*)d_in[6];
    const float* cw   = (const float*)d_in[7];
    const float* cb   = (const float*)d_in[8];
    float* out = (float*)d_out;

    // ws layout (floats): sbias_g@0 (2048) | weffb@2048 (589824 floats as bf16 pairs)
    float* sbias_g        = (float*)d_ws;
    unsigned short* weffb = (unsigned short*)((float*)d_ws + 2048);

    prep_kernel<<<dim3(256), dim3(256), 0, stream>>>(
        rv, W1, b1, W2, b2, emb, cw, cb, weffb, sbias_g);
    conv3_kernel<<<dim3(BATCH * 28), dim3(256), 0, stream>>>(
        x, weffb, sbias_g, out);
}

// Round 6
// 40.649 us; speedup vs baseline: 1.4950x; 1.2199x over previous
//
#include <hip/hip_runtime.h>
#include <hip/hip_bf16.h>
#include <stdint.h>

// Problem constants
#define BATCH 32
#define CIN   64
#define COUT  64
#define HIN   58
#define WIN   58
#define HOUT  56
#define WOUT  56
#define RSIZE 512
#define NB    10
#define EDIM  64
#define HID   128
#define CHW   (HIN*WIN)     // 3364
#define OHW   (HOUT*WOUT)   // 3136

typedef __attribute__((ext_vector_type(8)))  short short8;
typedef __attribute__((ext_vector_type(16))) float f32x16;

__device__ __forceinline__ unsigned short f2bf(float f) {
    unsigned int u = __builtin_bit_cast(unsigned int, f);
    u += 0x7fffu + ((u >> 16) & 1u);          // RNE
    return (unsigned short)(u >> 16);
}

// ---------------- Kernel 1: routing (1 block per batch, deep k-split) ----------------
__global__ __launch_bounds__(512) void route_kernel(
    const float* __restrict__ rv, const float* __restrict__ W1,
    const float* __restrict__ b1, const float* __restrict__ W2,
    const float* __restrict__ b2, const float* __restrict__ emb,
    float* __restrict__ wts)
{
    const int b = blockIdx.x;
    const int t = threadIdx.x;

    __shared__ float s_rv[RSIZE];
    __shared__ float s_part[4 * HID];    // reused as [8][64] for W2
    __shared__ float s_h[HID];
    __shared__ float s_r[EDIM];
    __shared__ float s_rn;
    __shared__ float s_sim[NB];

    if (t < 128) ((float4*)s_rv)[t] = ((const float4*)(rv + (size_t)b * RSIZE))[t];
    __syncthreads();

    // hidden partials: h = t&127, kq = t>>7 (4-way k split, 128 each)
    {
        const int h = t & 127, kq = t >> 7;
        float acc = 0.0f;
        const float* wp = W1 + (size_t)(kq * 128) * HID + h;
        const float* xp = s_rv + kq * 128;
        #pragma unroll 8
        for (int k = 0; k < 128; ++k) acc = fmaf(xp[k], wp[(size_t)k * HID], acc);
        s_part[kq * HID + h] = acc;
    }
    __syncthreads();
    if (t < HID)
        s_h[t] = fmaxf(s_part[t] + s_part[HID + t] + s_part[2 * HID + t] +
                       s_part[3 * HID + t] + b1[t], 0.0f);
    __syncthreads();

    // r partials: e = t&63, kq = t>>6 (8-way k split, 16 each)
    {
        const int e = t & 63, kq = t >> 6;
        float acc = 0.0f;
        const float* wp = W2 + (size_t)(kq * 16) * EDIM + e;
        const float* hp = s_h + kq * 16;
        #pragma unroll
        for (int k = 0; k < 16; ++k) acc = fmaf(hp[k], wp[(size_t)k * EDIM], acc);
        s_part[kq * 64 + e] = acc;
    }
    __syncthreads();
    if (t < EDIM) {
        float r = b2[t];
        #pragma unroll
        for (int q = 0; q < 8; ++q) r += s_part[q * 64 + t];
        s_r[t] = r;
    }
    __syncthreads();

    if (t < 64) {
        float sq = s_r[t] * s_r[t];
        #pragma unroll
        for (int off = 32; off; off >>= 1) sq += __shfl_xor(sq, off);
        if (t == 0) s_rn = sqrtf(sq);
    }
    __syncthreads();

    // cosine sims: wave wid handles n = wid, wid+8
    {
        const int wid = t >> 6, lane = t & 63;
        for (int n = wid; n < NB; n += 8) {
            const float ev = emb[n * EDIM + lane];
            float dot = ev * s_r[lane];
            float nb2 = ev * ev;
            #pragma unroll
            for (int off = 32; off; off >>= 1) {
                dot += __shfl_xor(dot, off);
                nb2 += __shfl_xor(nb2, off);
            }
            if (lane == 0)
                s_sim[n] = dot / ((s_rn + 1e-8f) * (sqrtf(nb2) + 1e-8f));
        }
    }
    __syncthreads();

    if (t == 0) {
        float m = -1e30f;
        #pragma unroll
        for (int n = 0; n < NB; ++n) m = fmaxf(m, s_sim[n]);
        float w[NB], sum = 0.0f;
        #pragma unroll
        for (int n = 0; n < NB; ++n) { w[n] = __expf(s_sim[n] - m); sum += w[n]; }
        const float inv = 1.0f / sum;
        float d = 0.0f;
        #pragma unroll
        for (int n = 0; n < NB; ++n) { w[n] *= inv; d += w[n]; }
        const float invd = 1.0f / d;
        #pragma unroll
        for (int n = 0; n < NB; ++n) wts[b * NB + n] = w[n] * invd;
    }
}

// ---------------- Kernel 2: weight mix -> weffb[b][s][ks][kg][co][8] ----------------
// 256 blocks: co = blk & 63, bq = blk >> 6. Same-co blocks share an XCD
// (bid%8 == co%8) -> cw slices fetched once into that XCD's L2.
__global__ __launch_bounds__(256) void wmix2_kernel(
    const float* __restrict__ cw, const float* __restrict__ cbias,
    const float* __restrict__ wts,
    unsigned short* __restrict__ weffb, float* __restrict__ sbias_g)
{
    const int co = blockIdx.x & 63;
    const int bq = blockIdx.x >> 6;
    const int t  = threadIdx.x;

    __shared__ float scw[NB * 576];      // 23 KB
    __shared__ float s_w[8 * NB];

    if (t < 8 * NB) s_w[t] = wts[bq * 8 * NB + t];
    for (int i = t; i < 1440; i += 256) {
        const int n = i / 144, r4 = i - n * 144;
        ((float4*)scw)[(size_t)n * 144 + r4] =
            *(const float4*)(cw + (size_t)(n * COUT + co) * 576 + r4 * 4);
    }
    __syncthreads();

    for (int i = t; i < 8 * 576; i += 256) {
        const int bl  = i / 576, rem = i - bl * 576;
        const int s   = rem >> 6, cin = rem & 63;
        float v = 0.0f;
        #pragma unroll
        for (int n = 0; n < NB; ++n)
            v = fmaf(s_w[bl * NB + n], scw[n * 576 + cin * 9 + s], v);
        const int b  = bq * 8 + bl;
        const int ks = cin >> 4, kg = (cin >> 3) & 1, c8 = cin & 7;
        weffb[((((size_t)(b * 9 + s) * 4 + ks) * 2 + kg) * 64 + co) * 8 + c8] = f2bf(v);
    }
    if (t < 8) {
        float v = 0.0f;
        #pragma unroll
        for (int n = 0; n < NB; ++n) v = fmaf(s_w[t * NB + n], cbias[n * COUT + co], v);
        sbias_g[(bq * 8 + t) * COUT + co] = v;
    }
}

// ---------------- Kernel 3: MFMA implicit-GEMM conv (unchanged from R5) ----------------
__global__ __launch_bounds__(256, 2) void conv3_kernel(
    const float* __restrict__ x, const unsigned short* __restrict__ weffb,
    const float* __restrict__ sbias_g, float* __restrict__ out)
{
    const int bid  = blockIdx.x;
    const int xcd  = bid & 7;
    const int slot = bid >> 3;
    const int b    = xcd + 8 * (slot / 28);
    const int tile = slot - (slot / 28) * 28;
    const int oh0  = tile * 2;

    const int t    = threadIdx.x;
    const int wid  = t >> 6;
    const int lane = t & 63;
    const int ln   = lane & 31;
    const int kg   = lane >> 5;

    __shared__ unsigned short xs[232 * 64];   // 29696 B
    __shared__ float sbias[COUT];

    if (t < COUT) sbias[t] = sbias_g[b * COUT + t];

    // stage full 232sp x 64cin tile, converting fp32->bf16 inline, XOR-swizzled
    const float* xg = x + (size_t)b * CIN * CHW + oh0 * WIN;
    #pragma unroll
    for (int k = 0; k < 8; ++k) {
        const int e = t + 256 * k;
        if (e < 1856) {
            const int cb = e / 232;
            const int sp = e - cb * 232;
            const float* gp = xg + (size_t)(cb * 8) * CHW + sp;
            short8 v;
            #pragma unroll
            for (int j = 0; j < 8; ++j)
                v[j] = (short)f2bf(gp[(size_t)j * CHW]);
            *(short8*)&xs[sp * 64 + (cb ^ (sp & 7)) * 8] = v;
        }
    }
    __syncthreads();

    const int p   = wid * 32 + ln;
    const bool valid = (p < 112);
    const int pc  = valid ? p : 111;
    const int r   = pc / 56, ow = pc - r * 56;
    const int sbase = r * WIN + ow;

    f32x16 acc[2];
    #pragma unroll
    for (int mt = 0; mt < 2; ++mt)
        #pragma unroll
        for (int j = 0; j < 16; ++j) acc[mt][j] = 0.0f;

    #pragma unroll
    for (int ks = 0; ks < 4; ++ks) {
        #pragma unroll
        for (int s = 0; s < 9; ++s) {
            const int kh = s / 3, kw = s - kh * 3;
            const unsigned short* ap =
                weffb + (((size_t)(b * 9 + s) * 4 + ks) * 2 + kg) * 512;
            const short8 a0 = *(const short8*)(ap + ln * 8);
            const short8 a1 = *(const short8*)(ap + (32 + ln) * 8);
            const int sp   = sbase + kh * WIN + kw;
            const int addr = (sp << 7) + ((((ks << 1) + kg) ^ (sp & 7)) << 4);
            const short8 bf = *(const short8*)((const char*)xs + addr);
            acc[0] = __builtin_amdgcn_mfma_f32_32x32x16_bf16(a0, bf, acc[0], 0, 0, 0);
            acc[1] = __builtin_amdgcn_mfma_f32_32x32x16_bf16(a1, bf, acc[1], 0, 0, 0);
        }
    }

    if (valid) {
        #pragma unroll
        for (int mt = 0; mt < 2; ++mt) {
            float* op = out + ((size_t)(b * COUT + mt * 32) * HOUT + oh0 + r) * WOUT + ow;
            #pragma unroll
            for (int reg = 0; reg < 16; ++reg) {
                const int co_l = (reg & 3) + 8 * (reg >> 2) + 4 * kg;
                op[(size_t)co_l * OHW] = acc[mt][reg] + sbias[mt * 32 + co_l];
            }
        }
    }
}

extern "C" void kernel_launch(void* const* d_in, const int* in_sizes, int n_in,
                              void* d_out, int out_size, void* d_ws, size_t ws_size,
                              hipStream_t stream) {
    const float* x    = (const float*)d_in[0];
    const float* rv   = (const float*)d_in[1];
    const float* W1   = (const float*)d_in[2];
    const float* b1   = (const float*)d_in[3];
    const float* W2   = (const float*)d_in[4];
    const float* b2   = (const float*)d_in[5];
    const float* emb  = (const float*)d_in[6];
    const float* cw   = (const float*)d_in[7];
    const float* cb   = (const float*)d_in[8];
    float* out = (float*)d_out;

    // ws layout (floats): wts@0 (320) | sbias_g@1024 (2048) | weffb@3072 (294912 floats as bf16)
    float* wts            = (float*)d_ws;
    float* sbias_g        = (float*)d_ws + 1024;
    unsigned short* weffb = (unsigned short*)((float*)d_ws + 3072);

    route_kernel<<<dim3(BATCH), dim3(512), 0, stream>>>(rv, W1, b1, W2, b2, emb, wts);
    wmix2_kernel<<<dim3(256), dim3(256), 0, stream>>>(cw, cb, wts, weffb, sbias_g);
    conv3_kernel<<<dim3(BATCH * 28), dim3(256), 0, stream>>>(x, weffb, sbias_g, out);
}